// Round 2
// baseline (1411.479 us; speedup 1.0000x reference)
//
#include <hip/hip_runtime.h>
#include <hip/hip_bf16.h>

#define F_IN 128
#define F_HID 64
#define F_OUT 128
#define BSH 9                 // 512 nodes per bucket
#define BS  (1 << BSH)
#define MAXNB 256

__device__ __forceinline__ int clampi(int v, int lo, int hi) {
    return v < lo ? lo : (v > hi ? hi : v);
}

// ---------------- zero init ----------------
__global__ void zero2_kernel(int* __restrict__ a, int* __restrict__ b, int n) {
    int i = blockIdx.x * blockDim.x + threadIdx.x;
    if (i < n) { a[i] = 0; b[i] = 0; }
}

// ---------------- B1: coarse bucket histogram ----------------
__global__ void bhist_kernel(const int* __restrict__ dst, int* __restrict__ bhist,
                             int E, int Nn, int NB) {
    __shared__ int lh[MAXNB];
    for (int i = threadIdx.x; i < NB; i += 256) lh[i] = 0;
    __syncthreads();
    int chunk = (E + gridDim.x - 1) / gridDim.x;
    int base = blockIdx.x * chunk;
    int end = base + chunk; if (end > E) end = E;
    for (int i = base + threadIdx.x; i < end; i += 256) {
        int d = clampi(dst[i], 0, Nn - 1);
        atomicAdd(&lh[d >> BSH], 1);
    }
    __syncthreads();
    for (int i = threadIdx.x; i < NB; i += 256)
        if (lh[i]) atomicAdd(&bhist[i], lh[i]);
}

// ---------------- exclusive scan over NB buckets (1 block) ----------------
__global__ void bscan_kernel(const int* __restrict__ bhist, int* __restrict__ bbase, int NB) {
    __shared__ int s[MAXNB];
    int t = threadIdx.x;                    // blockDim = 256
    int v = (t < NB) ? bhist[t] : 0;
    s[t] = v;
    __syncthreads();
    for (int d = 1; d < MAXNB; d <<= 1) {
        int x = (t >= d) ? s[t - d] : 0;
        __syncthreads();
        s[t] += x;
        __syncthreads();
    }
    if (t < NB) bbase[t] = s[t] - v;
}

// ---------------- B2: place edges into bucket staging (packed src|dstlo) ----------------
__global__ void bplace_kernel(const int* __restrict__ src, const int* __restrict__ dst,
                              const int* __restrict__ bbase, int* __restrict__ bcur,
                              int* __restrict__ staging, int E, int Nn, int NB) {
    __shared__ int lh[MAXNB];
    __shared__ int gb[MAXNB];
    for (int i = threadIdx.x; i < NB; i += 256) lh[i] = 0;
    __syncthreads();
    int chunk = (E + gridDim.x - 1) / gridDim.x;
    int base = blockIdx.x * chunk;
    int end = base + chunk; if (end > E) end = E;
    for (int i = base + threadIdx.x; i < end; i += 256) {
        int d = clampi(dst[i], 0, Nn - 1);
        atomicAdd(&lh[d >> BSH], 1);
    }
    __syncthreads();
    for (int i = threadIdx.x; i < NB; i += 256) {
        int c = lh[i];
        gb[i] = (c > 0) ? bbase[i] + atomicAdd(&bcur[i], c) : 0;
        lh[i] = 0;                               // reuse as local cursor
    }
    __syncthreads();
    for (int i = base + threadIdx.x; i < end; i += 256) {
        int d = clampi(dst[i], 0, Nn - 1);
        int s = clampi(src[i], 0, Nn - 1);
        int b = d >> BSH;
        int p = gb[b] + atomicAdd(&lh[b], 1);    // contiguous run per block*bucket
        staging[p] = (s << BSH) | (d & (BS - 1));
    }
}

// ---------------- C: per-bucket fine fill -> cnt/off/norm/csr ----------------
__global__ void bfine_kernel(const int* __restrict__ bhist, const int* __restrict__ bbase,
                             const int* __restrict__ staging,
                             int* __restrict__ cnt, int* __restrict__ off,
                             float* __restrict__ nrm, int* __restrict__ csr, int Nn) {
    __shared__ int lcnt[BS];
    __shared__ int loff[BS];
    __shared__ int lcur[BS];
    __shared__ int ps[256];
    int b = blockIdx.x;
    int t = threadIdx.x;
    int base  = bbase[b];
    int count = bhist[b];
    int node0 = b << BSH;

    for (int r = t; r < BS; r += 256) lcnt[r] = 0;
    __syncthreads();
    for (int i = t; i < count; i += 256)
        atomicAdd(&lcnt[staging[base + i] & (BS - 1)], 1);
    __syncthreads();

    // exclusive scan of lcnt[512] with 256 threads
    int a0 = lcnt[2 * t], a1 = lcnt[2 * t + 1];
    int pair = a0 + a1;
    ps[t] = pair;
    __syncthreads();
    for (int d = 1; d < 256; d <<= 1) {
        int x = (t >= d) ? ps[t - d] : 0;
        __syncthreads();
        ps[t] += x;
        __syncthreads();
    }
    int excl = ps[t] - pair;
    loff[2 * t]     = excl;
    loff[2 * t + 1] = excl + a0;
    __syncthreads();

    for (int r = t; r < BS; r += 256) {
        int node = node0 + r;
        if (node < Nn) {
            int c = lcnt[r];
            cnt[node] = c;
            off[node] = base + loff[r];
            nrm[node] = rsqrtf((float)c + 1.0f);
        }
        lcur[r] = 0;
    }
    __syncthreads();

    for (int i = t; i < count; i += 256) {
        int v = staging[base + i];
        int r = v & (BS - 1);
        int p = base + loff[r] + atomicAdd(&lcur[r], 1);
        csr[p] = v >> BSH;
    }
}

// ---------------- register-tiled f32 GEMM, v3 ----------------
// v1 (67us/gemm) was latency-bound from grid starvation: RB=128 -> 782 blocks
// = 3.05 blocks/CU, Occupancy 23%, VALUBusy 21%.
// v2's restructure (RPT=2 + prefetch + launch_bounds) triggered a compiler
// pathology: scratch storm (FETCH=WRITE=1.65GB, VALUBusy 1.2%). REVERTED.
// v3 keeps the v1 body byte-for-byte in structure (RPT=4 rows/thread, zero-fill
// OOB rows, no launch_bounds, no explicit prefetch) and doubles wave count by
// narrowing the column tile: CT = N/4 (4 cols/thread, acc[4][4]).
//   layer-1: RB=64 -> 1563 blocks; layer-2: RB=32 -> 3125 blocks.
// LDS 32KB caps 5 blocks/CU -> ~20 waves/CU reachable (was ~12 peak).
template<int K, int N, bool PRESCALE, bool BIAS>
__global__ void gemm_tiled(const float* __restrict__ A, const float* __restrict__ B,
                           const float* __restrict__ nrm, const float* __restrict__ bias,
                           float* __restrict__ C, int M) {
    constexpr int CT = N / 4;          // col-tiles of 4 cols
    constexpr int RB = (256 / CT) * 4; // rows per block
    __shared__ float Ws[K * N];        // 32 KB for both layer shapes

    int tid = threadIdx.x;
    for (int i = tid; i < K * N / 4; i += 256)
        ((float4*)Ws)[i] = ((const float4*)B)[i];
    __syncthreads();

    int ct = tid % CT;
    int rt = tid / CT;
    int row0 = blockIdx.x * RB + rt * 4;
    int c0 = ct * 4;

    float acc[4][4];
#pragma unroll
    for (int r = 0; r < 4; r++)
#pragma unroll
        for (int c = 0; c < 4; c++) acc[r][c] = 0.f;

    for (int kk = 0; kk < K; kk += 4) {
        float4 av[4];
#pragma unroll
        for (int r = 0; r < 4; r++) {
            int row = row0 + r;
            av[r] = (row < M) ? *(const float4*)(A + (size_t)row * K + kk)
                              : make_float4(0.f, 0.f, 0.f, 0.f);
        }
#pragma unroll
        for (int j = 0; j < 4; j++) {
            float4 w = *(const float4*)(Ws + (kk + j) * N + c0);
            float wj[4] = {w.x, w.y, w.z, w.w};
#pragma unroll
            for (int r = 0; r < 4; r++) {
                float a = (j == 0) ? av[r].x : (j == 1) ? av[r].y : (j == 2) ? av[r].z : av[r].w;
#pragma unroll
                for (int c = 0; c < 4; c++)
                    acc[r][c] = fmaf(a, wj[c], acc[r][c]);
            }
        }
    }

    float bcol[4];
    if (BIAS) {
        float4 bb = *(const float4*)(bias + c0);
        bcol[0]=bb.x; bcol[1]=bb.y; bcol[2]=bb.z; bcol[3]=bb.w;
    }

#pragma unroll
    for (int r = 0; r < 4; r++) {
        int row = row0 + r;
        if (row >= M) continue;
        float scale = PRESCALE ? nrm[row] : 1.0f;
        float4 o;
        o.x = acc[r][0]; o.y = acc[r][1]; o.z = acc[r][2]; o.w = acc[r][3];
        if (PRESCALE) { o.x*=scale; o.y*=scale; o.z*=scale; o.w*=scale; }
        if (BIAS)     { o.x+=bcol[0]; o.y+=bcol[1]; o.z+=bcol[2]; o.w+=bcol[3]; }
        *(float4*)(C + (size_t)row * N + c0) = o;
    }
}

// ---------------- per-node CSR gather: ONE WAVE PER NODE (64 lanes = 64 feats) ----------------
// CONV:  out_i = norm_i * relu( norm_i*(sum + self) + bias )   [emits p]
// !CONV: out_i = norm_i * (sum + self)                          [emits q]
// node is wave-uniform (readfirstlane) -> off/cnt/csr go through the scalar path;
// edge loop unrolled x8 -> 8 outstanding random h-row loads per wave.
template<bool CONV>
__global__ void gather64_kernel(const float* __restrict__ h, const float* __restrict__ norm,
                                const int* __restrict__ off, const int* __restrict__ cnt,
                                const int* __restrict__ csr_src,
                                const float* __restrict__ bias,
                                float* __restrict__ out, int Nn, int E) {
    int wave = (blockIdx.x * blockDim.x + threadIdx.x) >> 6;
    int lane = threadIdx.x & 63;
    int node = __builtin_amdgcn_readfirstlane(wave);
    if (node >= Nn) return;

    int o0 = __builtin_amdgcn_readfirstlane(off[node]);
    int c  = __builtin_amdgcn_readfirstlane(cnt[node]);
    if (c < 0) c = 0;
    if (o0 < 0) o0 = 0;
    if (o0 + c > E) c = E - o0;

    const int* ce = csr_src + o0;
    float sum = 0.0f;
    int e = 0;
    for (; e + 8 <= c; e += 8) {
        int s0 = clampi(ce[e],     0, Nn - 1);
        int s1 = clampi(ce[e + 1], 0, Nn - 1);
        int s2 = clampi(ce[e + 2], 0, Nn - 1);
        int s3 = clampi(ce[e + 3], 0, Nn - 1);
        int s4 = clampi(ce[e + 4], 0, Nn - 1);
        int s5 = clampi(ce[e + 5], 0, Nn - 1);
        int s6 = clampi(ce[e + 6], 0, Nn - 1);
        int s7 = clampi(ce[e + 7], 0, Nn - 1);
        float v0 = h[(size_t)s0 * 64 + lane];
        float v1 = h[(size_t)s1 * 64 + lane];
        float v2 = h[(size_t)s2 * 64 + lane];
        float v3 = h[(size_t)s3 * 64 + lane];
        float v4 = h[(size_t)s4 * 64 + lane];
        float v5 = h[(size_t)s5 * 64 + lane];
        float v6 = h[(size_t)s6 * 64 + lane];
        float v7 = h[(size_t)s7 * 64 + lane];
        sum += v0; sum += v1; sum += v2; sum += v3;
        sum += v4; sum += v5; sum += v6; sum += v7;
    }
    for (; e + 4 <= c; e += 4) {
        int s0 = clampi(ce[e],     0, Nn - 1);
        int s1 = clampi(ce[e + 1], 0, Nn - 1);
        int s2 = clampi(ce[e + 2], 0, Nn - 1);
        int s3 = clampi(ce[e + 3], 0, Nn - 1);
        float v0 = h[(size_t)s0 * 64 + lane];
        float v1 = h[(size_t)s1 * 64 + lane];
        float v2 = h[(size_t)s2 * 64 + lane];
        float v3 = h[(size_t)s3 * 64 + lane];
        sum += v0; sum += v1; sum += v2; sum += v3;
    }
    for (; e < c; e++) {
        int s = clampi(ce[e], 0, Nn - 1);
        sum += h[(size_t)s * 64 + lane];
    }
    float self = h[(size_t)node * 64 + lane];
    float nv = norm[node];
    float r = nv * (sum + self);
    if (CONV) r = nv * fmaxf(r + bias[lane], 0.0f);
    out[(size_t)node * 64 + lane] = r;
}

extern "C" void kernel_launch(void* const* d_in, const int* in_sizes, int n_in,
                              void* d_out, int out_size, void* d_ws, size_t ws_size,
                              hipStream_t stream) {
    if (n_in < 6) return;
    const float* x   = (const float*)d_in[0];   // [N,128] f32
    const int*   ei  = (const int*)d_in[1];     // [2,E] int32
    const float* W1  = (const float*)d_in[2];   // [128,64] f32
    const float* b1  = (const float*)d_in[3];   // [64] f32
    const float* W2  = (const float*)d_in[4];   // [64,128] f32
    const float* b2  = (const float*)d_in[5];   // [128] f32
    float*       out = (float*)d_out;           // [N,128] f32

    int Nn = in_sizes[0] / F_IN;
    int E  = in_sizes[1] / 2;
    const int* src = ei;
    const int* dst = ei + E;

    int NB = (Nn + BS - 1) >> BSH;              // 196 for 100k
    if (NB > MAXNB) return;
    if (Nn > (1 << (31 - BSH))) return;

    // ---- workspace layout (~40 MB), guarded ----
    size_t o = 0;
    auto alloc = [&](size_t bytes) { size_t cur = o; o += (bytes + 255) & ~(size_t)255; return cur; };
    size_t o_cnt   = alloc((size_t)Nn * 4);
    size_t o_off   = alloc((size_t)Nn * 4);
    size_t o_nrm   = alloc((size_t)Nn * 4);
    size_t o_csr   = alloc((size_t)E * 4);
    size_t o_stg   = alloc((size_t)E * 4);
    size_t o_bh    = alloc(MAXNB * 4);
    size_t o_bb    = alloc(MAXNB * 4);
    size_t o_bc    = alloc(MAXNB * 4);
    size_t o_h     = alloc((size_t)Nn * F_HID * 4);
    if (o > ws_size) return;

    char* ws = (char*)d_ws;
    int*   cnt   = (int*)(ws + o_cnt);
    int*   off   = (int*)(ws + o_off);
    float* nrm   = (float*)(ws + o_nrm);
    int*   csr   = (int*)(ws + o_csr);
    int*   stg   = (int*)(ws + o_stg);
    int*   bh    = (int*)(ws + o_bh);
    int*   bb    = (int*)(ws + o_bb);
    int*   bc    = (int*)(ws + o_bc);
    float* h1    = (float*)(ws + o_h);
    float* q     = (float*)(ws + o_h);          // overlays h1 (dead by then)
    float* p     = out + (size_t)Nn * F_HID;    // upper half of d_out, dead before gemm2

    // ---- CSR build (bucketed, write-local) ----
    zero2_kernel<<<1, 256, 0, stream>>>(bh, bc, MAXNB);
    bhist_kernel<<<256, 256, 0, stream>>>(dst, bh, E, Nn, NB);
    bscan_kernel<<<1, 256, 0, stream>>>(bh, bb, NB);
    bplace_kernel<<<256, 256, 0, stream>>>(src, dst, bb, bc, stg, E, Nn, NB);
    bfine_kernel<<<NB, 256, 0, stream>>>(bh, bb, stg, cnt, off, nrm, csr, Nn);

    // ---- layer 1: h1 = (x@W1)*norm ; p = norm*relu(norm*(sum+self)+b1) ----
    {
        constexpr int RB = (256 / (F_HID / 4)) * 4;  // 64 rows/block -> 1563 blocks
        gemm_tiled<F_IN, F_HID, true, false><<<(Nn + RB - 1) / RB, 256, 0, stream>>>(
            x, W1, nrm, nullptr, h1, Nn);
    }
    gather64_kernel<true><<<(Nn + 3) / 4, 256, 0, stream>>>(
        h1, nrm, off, cnt, csr, b1, p, Nn, E);

    // ---- layer 2: q = norm*(sum_p+p) ; out = q@W2 + b2 ----
    gather64_kernel<false><<<(Nn + 3) / 4, 256, 0, stream>>>(
        p, nrm, off, cnt, csr, nullptr, q, Nn, E);
    {
        constexpr int RB = (256 / (F_OUT / 4)) * 4;  // 32 rows/block -> 3125 blocks
        gemm_tiled<F_HID, F_OUT, false, true><<<(Nn + RB - 1) / RB, 256, 0, stream>>>(
            q, W2, nullptr, b2, out, Nn);
    }
}

// Round 3
// 360.742 us; speedup vs baseline: 3.9127x; 3.9127x over previous
//
#include <hip/hip_runtime.h>
#include <hip/hip_bf16.h>

#define F_IN 128
#define F_HID 64
#define F_OUT 128
#define BSH 9                 // 512 nodes per bucket
#define BS  (1 << BSH)
#define MAXNB 256

__device__ __forceinline__ int clampi(int v, int lo, int hi) {
    return v < lo ? lo : (v > hi ? hi : v);
}

// ---------------- zero init ----------------
__global__ void zero2_kernel(int* __restrict__ a, int* __restrict__ b, int n) {
    int i = blockIdx.x * blockDim.x + threadIdx.x;
    if (i < n) { a[i] = 0; b[i] = 0; }
}

// ---------------- B1: coarse bucket histogram ----------------
__global__ void bhist_kernel(const int* __restrict__ dst, int* __restrict__ bhist,
                             int E, int Nn, int NB) {
    __shared__ int lh[MAXNB];
    for (int i = threadIdx.x; i < NB; i += 256) lh[i] = 0;
    __syncthreads();
    int chunk = (E + gridDim.x - 1) / gridDim.x;
    int base = blockIdx.x * chunk;
    int end = base + chunk; if (end > E) end = E;
    for (int i = base + threadIdx.x; i < end; i += 256) {
        int d = clampi(dst[i], 0, Nn - 1);
        atomicAdd(&lh[d >> BSH], 1);
    }
    __syncthreads();
    for (int i = threadIdx.x; i < NB; i += 256)
        if (lh[i]) atomicAdd(&bhist[i], lh[i]);
}

// ---------------- exclusive scan over NB buckets (1 block) ----------------
__global__ void bscan_kernel(const int* __restrict__ bhist, int* __restrict__ bbase, int NB) {
    __shared__ int s[MAXNB];
    int t = threadIdx.x;                    // blockDim = 256
    int v = (t < NB) ? bhist[t] : 0;
    s[t] = v;
    __syncthreads();
    for (int d = 1; d < MAXNB; d <<= 1) {
        int x = (t >= d) ? s[t - d] : 0;
        __syncthreads();
        s[t] += x;
        __syncthreads();
    }
    if (t < NB) bbase[t] = s[t] - v;
}

// ---------------- B2: place edges into bucket staging (packed src|dstlo) ----------------
__global__ void bplace_kernel(const int* __restrict__ src, const int* __restrict__ dst,
                              const int* __restrict__ bbase, int* __restrict__ bcur,
                              int* __restrict__ staging, int E, int Nn, int NB) {
    __shared__ int lh[MAXNB];
    __shared__ int gb[MAXNB];
    for (int i = threadIdx.x; i < NB; i += 256) lh[i] = 0;
    __syncthreads();
    int chunk = (E + gridDim.x - 1) / gridDim.x;
    int base = blockIdx.x * chunk;
    int end = base + chunk; if (end > E) end = E;
    for (int i = base + threadIdx.x; i < end; i += 256) {
        int d = clampi(dst[i], 0, Nn - 1);
        atomicAdd(&lh[d >> BSH], 1);
    }
    __syncthreads();
    for (int i = threadIdx.x; i < NB; i += 256) {
        int c = lh[i];
        gb[i] = (c > 0) ? bbase[i] + atomicAdd(&bcur[i], c) : 0;
        lh[i] = 0;                               // reuse as local cursor
    }
    __syncthreads();
    for (int i = base + threadIdx.x; i < end; i += 256) {
        int d = clampi(dst[i], 0, Nn - 1);
        int s = clampi(src[i], 0, Nn - 1);
        int b = d >> BSH;
        int p = gb[b] + atomicAdd(&lh[b], 1);    // contiguous run per block*bucket
        staging[p] = (s << BSH) | (d & (BS - 1));
    }
}

// ---------------- C: per-bucket fine fill -> cnt/off/norm/csr ----------------
__global__ void bfine_kernel(const int* __restrict__ bhist, const int* __restrict__ bbase,
                             const int* __restrict__ staging,
                             int* __restrict__ cnt, int* __restrict__ off,
                             float* __restrict__ nrm, int* __restrict__ csr, int Nn) {
    __shared__ int lcnt[BS];
    __shared__ int loff[BS];
    __shared__ int lcur[BS];
    __shared__ int ps[256];
    int b = blockIdx.x;
    int t = threadIdx.x;
    int base  = bbase[b];
    int count = bhist[b];
    int node0 = b << BSH;

    for (int r = t; r < BS; r += 256) lcnt[r] = 0;
    __syncthreads();
    for (int i = t; i < count; i += 256)
        atomicAdd(&lcnt[staging[base + i] & (BS - 1)], 1);
    __syncthreads();

    // exclusive scan of lcnt[512] with 256 threads
    int a0 = lcnt[2 * t], a1 = lcnt[2 * t + 1];
    int pair = a0 + a1;
    ps[t] = pair;
    __syncthreads();
    for (int d = 1; d < 256; d <<= 1) {
        int x = (t >= d) ? ps[t - d] : 0;
        __syncthreads();
        ps[t] += x;
        __syncthreads();
    }
    int excl = ps[t] - pair;
    loff[2 * t]     = excl;
    loff[2 * t + 1] = excl + a0;
    __syncthreads();

    for (int r = t; r < BS; r += 256) {
        int node = node0 + r;
        if (node < Nn) {
            int c = lcnt[r];
            cnt[node] = c;
            off[node] = base + loff[r];
            nrm[node] = rsqrtf((float)c + 1.0f);
        }
        lcur[r] = 0;
    }
    __syncthreads();

    for (int i = t; i < count; i += 256) {
        int v = staging[base + i];
        int r = v & (BS - 1);
        int p = base + loff[r] + atomicAdd(&lcur[r], 1);
        csr[p] = v >> BSH;
    }
}

// ---------------- register-tiled f32 GEMM, v4 ----------------
// History:
//  v1 (round 0): CT=8 cols, RB=128/64, grid 782/1563 -> 67us/gemm, FETCH 32MB,
//     VALUBusy 21%, Occ 23%. Latency-bound (A-load stall per kk-step).
//  v2/v3 (rounds 1-2): geometry changes (RB halved, grid 2x) -> one gemm at
//     ~1055us with 3.36GB device traffic @3.2TB/s, VALUBusy ~2%, duration
//     independent of occupancy (1.9% and 44% both 1060us). Neither structure
//     explains the bytes; TCC counters are device-wide -> suspected node/HBM
//     contention, but geometry is the only shared code delta. REVERTED.
//  v4: EXACT round-0 geometry (CT=8, RB=128/64, grid 782/1563, no
//     launch_bounds, conditional zero-fill loads). Single change: kk-unroll
//     4 -> 8, so 8 independent A float4 loads are in flight per step instead
//     of 4, halving the exposed-HBM-latency fraction that round-0's
//     VALUBusy=21% showed.
template<int K, int N, bool PRESCALE, bool BIAS>
__global__ void gemm_tiled(const float* __restrict__ A, const float* __restrict__ B,
                           const float* __restrict__ nrm, const float* __restrict__ bias,
                           float* __restrict__ C, int M) {
    constexpr int CT = N / 8;
    constexpr int RB = (256 / CT) * 4;
    __shared__ float Ws[K * N];

    int tid = threadIdx.x;
    for (int i = tid; i < K * N / 4; i += 256)
        ((float4*)Ws)[i] = ((const float4*)B)[i];
    __syncthreads();

    int ct = tid % CT;
    int rt = tid / CT;
    int row0 = blockIdx.x * RB + rt * 4;
    int c0 = ct * 8;

    float acc[4][8];
#pragma unroll
    for (int r = 0; r < 4; r++)
#pragma unroll
        for (int c = 0; c < 8; c++) acc[r][c] = 0.f;

    for (int kk = 0; kk < K; kk += 8) {
        float4 av[4], av2[4];
#pragma unroll
        for (int r = 0; r < 4; r++) {
            int row = row0 + r;
            if (row < M) {
                av[r]  = *(const float4*)(A + (size_t)row * K + kk);
                av2[r] = *(const float4*)(A + (size_t)row * K + kk + 4);
            } else {
                av[r]  = make_float4(0.f, 0.f, 0.f, 0.f);
                av2[r] = make_float4(0.f, 0.f, 0.f, 0.f);
            }
        }
#pragma unroll
        for (int j = 0; j < 4; j++) {
            const float* wrow = Ws + (kk + j) * N + c0;
            float4 w0 = *(const float4*)(wrow);
            float4 w1 = *(const float4*)(wrow + 4);
            float wj[8] = {w0.x, w0.y, w0.z, w0.w, w1.x, w1.y, w1.z, w1.w};
#pragma unroll
            for (int r = 0; r < 4; r++) {
                float a = (j == 0) ? av[r].x : (j == 1) ? av[r].y : (j == 2) ? av[r].z : av[r].w;
#pragma unroll
                for (int c = 0; c < 8; c++)
                    acc[r][c] = fmaf(a, wj[c], acc[r][c]);
            }
        }
#pragma unroll
        for (int j = 0; j < 4; j++) {
            const float* wrow = Ws + (kk + 4 + j) * N + c0;
            float4 w0 = *(const float4*)(wrow);
            float4 w1 = *(const float4*)(wrow + 4);
            float wj[8] = {w0.x, w0.y, w0.z, w0.w, w1.x, w1.y, w1.z, w1.w};
#pragma unroll
            for (int r = 0; r < 4; r++) {
                float a = (j == 0) ? av2[r].x : (j == 1) ? av2[r].y : (j == 2) ? av2[r].z : av2[r].w;
#pragma unroll
                for (int c = 0; c < 8; c++)
                    acc[r][c] = fmaf(a, wj[c], acc[r][c]);
            }
        }
    }

    float bcol[8];
    if (BIAS) {
        float4 bb0 = *(const float4*)(bias + c0);
        float4 bb1 = *(const float4*)(bias + c0 + 4);
        bcol[0]=bb0.x; bcol[1]=bb0.y; bcol[2]=bb0.z; bcol[3]=bb0.w;
        bcol[4]=bb1.x; bcol[5]=bb1.y; bcol[6]=bb1.z; bcol[7]=bb1.w;
    }

#pragma unroll
    for (int r = 0; r < 4; r++) {
        int row = row0 + r;
        if (row >= M) continue;
        float scale = PRESCALE ? nrm[row] : 1.0f;
        float4 o0, o1;
        o0.x = acc[r][0]; o0.y = acc[r][1]; o0.z = acc[r][2]; o0.w = acc[r][3];
        o1.x = acc[r][4]; o1.y = acc[r][5]; o1.z = acc[r][6]; o1.w = acc[r][7];
        if (PRESCALE) {
            o0.x*=scale; o0.y*=scale; o0.z*=scale; o0.w*=scale;
            o1.x*=scale; o1.y*=scale; o1.z*=scale; o1.w*=scale;
        }
        if (BIAS) {
            o0.x+=bcol[0]; o0.y+=bcol[1]; o0.z+=bcol[2]; o0.w+=bcol[3];
            o1.x+=bcol[4]; o1.y+=bcol[5]; o1.z+=bcol[6]; o1.w+=bcol[7];
        }
        float* crow = C + (size_t)row * N + c0;
        *(float4*)(crow) = o0;
        *(float4*)(crow + 4) = o1;
    }
}

// ---------------- per-node CSR gather: ONE WAVE PER NODE (64 lanes = 64 feats) ----------------
// CONV:  out_i = norm_i * relu( norm_i*(sum + self) + bias )   [emits p]
// !CONV: out_i = norm_i * (sum + self)                          [emits q]
// node is wave-uniform (readfirstlane) -> off/cnt/csr go through the scalar path;
// edge loop unrolled x8 -> 8 outstanding random h-row loads per wave.
template<bool CONV>
__global__ void gather64_kernel(const float* __restrict__ h, const float* __restrict__ norm,
                                const int* __restrict__ off, const int* __restrict__ cnt,
                                const int* __restrict__ csr_src,
                                const float* __restrict__ bias,
                                float* __restrict__ out, int Nn, int E) {
    int wave = (blockIdx.x * blockDim.x + threadIdx.x) >> 6;
    int lane = threadIdx.x & 63;
    int node = __builtin_amdgcn_readfirstlane(wave);
    if (node >= Nn) return;

    int o0 = __builtin_amdgcn_readfirstlane(off[node]);
    int c  = __builtin_amdgcn_readfirstlane(cnt[node]);
    if (c < 0) c = 0;
    if (o0 < 0) o0 = 0;
    if (o0 + c > E) c = E - o0;

    const int* ce = csr_src + o0;
    float sum = 0.0f;
    int e = 0;
    for (; e + 8 <= c; e += 8) {
        int s0 = clampi(ce[e],     0, Nn - 1);
        int s1 = clampi(ce[e + 1], 0, Nn - 1);
        int s2 = clampi(ce[e + 2], 0, Nn - 1);
        int s3 = clampi(ce[e + 3], 0, Nn - 1);
        int s4 = clampi(ce[e + 4], 0, Nn - 1);
        int s5 = clampi(ce[e + 5], 0, Nn - 1);
        int s6 = clampi(ce[e + 6], 0, Nn - 1);
        int s7 = clampi(ce[e + 7], 0, Nn - 1);
        float v0 = h[(size_t)s0 * 64 + lane];
        float v1 = h[(size_t)s1 * 64 + lane];
        float v2 = h[(size_t)s2 * 64 + lane];
        float v3 = h[(size_t)s3 * 64 + lane];
        float v4 = h[(size_t)s4 * 64 + lane];
        float v5 = h[(size_t)s5 * 64 + lane];
        float v6 = h[(size_t)s6 * 64 + lane];
        float v7 = h[(size_t)s7 * 64 + lane];
        sum += v0; sum += v1; sum += v2; sum += v3;
        sum += v4; sum += v5; sum += v6; sum += v7;
    }
    for (; e + 4 <= c; e += 4) {
        int s0 = clampi(ce[e],     0, Nn - 1);
        int s1 = clampi(ce[e + 1], 0, Nn - 1);
        int s2 = clampi(ce[e + 2], 0, Nn - 1);
        int s3 = clampi(ce[e + 3], 0, Nn - 1);
        float v0 = h[(size_t)s0 * 64 + lane];
        float v1 = h[(size_t)s1 * 64 + lane];
        float v2 = h[(size_t)s2 * 64 + lane];
        float v3 = h[(size_t)s3 * 64 + lane];
        sum += v0; sum += v1; sum += v2; sum += v3;
    }
    for (; e < c; e++) {
        int s = clampi(ce[e], 0, Nn - 1);
        sum += h[(size_t)s * 64 + lane];
    }
    float self = h[(size_t)node * 64 + lane];
    float nv = norm[node];
    float r = nv * (sum + self);
    if (CONV) r = nv * fmaxf(r + bias[lane], 0.0f);
    out[(size_t)node * 64 + lane] = r;
}

extern "C" void kernel_launch(void* const* d_in, const int* in_sizes, int n_in,
                              void* d_out, int out_size, void* d_ws, size_t ws_size,
                              hipStream_t stream) {
    if (n_in < 6) return;
    const float* x   = (const float*)d_in[0];   // [N,128] f32
    const int*   ei  = (const int*)d_in[1];     // [2,E] int32
    const float* W1  = (const float*)d_in[2];   // [128,64] f32
    const float* b1  = (const float*)d_in[3];   // [64] f32
    const float* W2  = (const float*)d_in[4];   // [64,128] f32
    const float* b2  = (const float*)d_in[5];   // [128] f32
    float*       out = (float*)d_out;           // [N,128] f32

    int Nn = in_sizes[0] / F_IN;
    int E  = in_sizes[1] / 2;
    const int* src = ei;
    const int* dst = ei + E;

    int NB = (Nn + BS - 1) >> BSH;              // 196 for 100k
    if (NB > MAXNB) return;
    if (Nn > (1 << (31 - BSH))) return;

    // ---- workspace layout (~40 MB), guarded ----
    size_t o = 0;
    auto alloc = [&](size_t bytes) { size_t cur = o; o += (bytes + 255) & ~(size_t)255; return cur; };
    size_t o_cnt   = alloc((size_t)Nn * 4);
    size_t o_off   = alloc((size_t)Nn * 4);
    size_t o_nrm   = alloc((size_t)Nn * 4);
    size_t o_csr   = alloc((size_t)E * 4);
    size_t o_stg   = alloc((size_t)E * 4);
    size_t o_bh    = alloc(MAXNB * 4);
    size_t o_bb    = alloc(MAXNB * 4);
    size_t o_bc    = alloc(MAXNB * 4);
    size_t o_h     = alloc((size_t)Nn * F_HID * 4);
    if (o > ws_size) return;

    char* ws = (char*)d_ws;
    int*   cnt   = (int*)(ws + o_cnt);
    int*   off   = (int*)(ws + o_off);
    float* nrm   = (float*)(ws + o_nrm);
    int*   csr   = (int*)(ws + o_csr);
    int*   stg   = (int*)(ws + o_stg);
    int*   bh    = (int*)(ws + o_bh);
    int*   bb    = (int*)(ws + o_bb);
    int*   bc    = (int*)(ws + o_bc);
    float* h1    = (float*)(ws + o_h);
    float* q     = (float*)(ws + o_h);          // overlays h1 (dead by then)
    float* p     = out + (size_t)Nn * F_HID;    // upper half of d_out, dead before gemm2

    // ---- CSR build (bucketed, write-local) ----
    zero2_kernel<<<1, 256, 0, stream>>>(bh, bc, MAXNB);
    bhist_kernel<<<256, 256, 0, stream>>>(dst, bh, E, Nn, NB);
    bscan_kernel<<<1, 256, 0, stream>>>(bh, bb, NB);
    bplace_kernel<<<256, 256, 0, stream>>>(src, dst, bb, bc, stg, E, Nn, NB);
    bfine_kernel<<<NB, 256, 0, stream>>>(bh, bb, stg, cnt, off, nrm, csr, Nn);

    // ---- layer 1: h1 = (x@W1)*norm ; p = norm*relu(norm*(sum+self)+b1) ----
    {
        constexpr int RB = (256 / (F_HID / 8)) * 4;  // 128 rows/block -> 782 blocks
        gemm_tiled<F_IN, F_HID, true, false><<<(Nn + RB - 1) / RB, 256, 0, stream>>>(
            x, W1, nrm, nullptr, h1, Nn);
    }
    gather64_kernel<true><<<(Nn + 3) / 4, 256, 0, stream>>>(
        h1, nrm, off, cnt, csr, b1, p, Nn, E);

    // ---- layer 2: q = norm*(sum_p+p) ; out = q@W2 + b2 ----
    gather64_kernel<false><<<(Nn + 3) / 4, 256, 0, stream>>>(
        p, nrm, off, cnt, csr, nullptr, q, Nn, E);
    {
        constexpr int RB = (256 / (F_OUT / 8)) * 4;  // 64 rows/block -> 1563 blocks
        gemm_tiled<F_HID, F_OUT, false, true><<<(Nn + RB - 1) / RB, 256, 0, stream>>>(
            q, W2, nullptr, b2, out, Nn);
    }
}

// Round 4
// 331.286 us; speedup vs baseline: 4.2606x; 1.0889x over previous
//
#include <hip/hip_runtime.h>
#include <hip/hip_bf16.h>

#define F_IN 128
#define F_HID 64
#define F_OUT 128
#define BSH 9                 // 512 nodes per bucket
#define BS  (1 << BSH)
#define MAXNB 256

__device__ __forceinline__ int clampi(int v, int lo, int hi) {
    return v < lo ? lo : (v > hi ? hi : v);
}

// RNE float->bf16 (explicit, no dependence on hip_bf16 ABI)
__device__ __forceinline__ unsigned short f2bf(float f) {
    unsigned int u = __float_as_uint(f);
    u = (u + 0x7FFFu + ((u >> 16) & 1u)) >> 16;
    return (unsigned short)u;
}
__device__ __forceinline__ float bf2f(unsigned short s) {
    return __uint_as_float(((unsigned int)s) << 16);
}

// ---------------- zero init ----------------
__global__ void zero2_kernel(int* __restrict__ a, int* __restrict__ b, int n) {
    int i = blockIdx.x * blockDim.x + threadIdx.x;
    if (i < n) { a[i] = 0; b[i] = 0; }
}

// ---------------- B1: coarse bucket histogram ----------------
__global__ void bhist_kernel(const int* __restrict__ dst, int* __restrict__ bhist,
                             int E, int Nn, int NB) {
    __shared__ int lh[MAXNB];
    for (int i = threadIdx.x; i < NB; i += 256) lh[i] = 0;
    __syncthreads();
    int chunk = (E + gridDim.x - 1) / gridDim.x;
    int base = blockIdx.x * chunk;
    int end = base + chunk; if (end > E) end = E;
    for (int i = base + threadIdx.x; i < end; i += 256) {
        int d = clampi(dst[i], 0, Nn - 1);
        atomicAdd(&lh[d >> BSH], 1);
    }
    __syncthreads();
    for (int i = threadIdx.x; i < NB; i += 256)
        if (lh[i]) atomicAdd(&bhist[i], lh[i]);
}

// ---------------- exclusive scan over NB buckets (1 block) ----------------
__global__ void bscan_kernel(const int* __restrict__ bhist, int* __restrict__ bbase, int NB) {
    __shared__ int s[MAXNB];
    int t = threadIdx.x;                    // blockDim = 256
    int v = (t < NB) ? bhist[t] : 0;
    s[t] = v;
    __syncthreads();
    for (int d = 1; d < MAXNB; d <<= 1) {
        int x = (t >= d) ? s[t - d] : 0;
        __syncthreads();
        s[t] += x;
        __syncthreads();
    }
    if (t < NB) bbase[t] = s[t] - v;
}

// ---------------- B2: place edges into bucket staging (packed src|dstlo) ----------------
__global__ void bplace_kernel(const int* __restrict__ src, const int* __restrict__ dst,
                              const int* __restrict__ bbase, int* __restrict__ bcur,
                              int* __restrict__ staging, int E, int Nn, int NB) {
    __shared__ int lh[MAXNB];
    __shared__ int gb[MAXNB];
    for (int i = threadIdx.x; i < NB; i += 256) lh[i] = 0;
    __syncthreads();
    int chunk = (E + gridDim.x - 1) / gridDim.x;
    int base = blockIdx.x * chunk;
    int end = base + chunk; if (end > E) end = E;
    for (int i = base + threadIdx.x; i < end; i += 256) {
        int d = clampi(dst[i], 0, Nn - 1);
        atomicAdd(&lh[d >> BSH], 1);
    }
    __syncthreads();
    for (int i = threadIdx.x; i < NB; i += 256) {
        int c = lh[i];
        gb[i] = (c > 0) ? bbase[i] + atomicAdd(&bcur[i], c) : 0;
        lh[i] = 0;                               // reuse as local cursor
    }
    __syncthreads();
    for (int i = base + threadIdx.x; i < end; i += 256) {
        int d = clampi(dst[i], 0, Nn - 1);
        int s = clampi(src[i], 0, Nn - 1);
        int b = d >> BSH;
        int p = gb[b] + atomicAdd(&lh[b], 1);    // contiguous run per block*bucket
        staging[p] = (s << BSH) | (d & (BS - 1));
    }
}

// ---------------- C: per-bucket fine fill -> cnt/off/norm/csr ----------------
__global__ void bfine_kernel(const int* __restrict__ bhist, const int* __restrict__ bbase,
                             const int* __restrict__ staging,
                             int* __restrict__ cnt, int* __restrict__ off,
                             float* __restrict__ nrm, int* __restrict__ csr, int Nn) {
    __shared__ int lcnt[BS];
    __shared__ int loff[BS];
    __shared__ int lcur[BS];
    __shared__ int ps[256];
    int b = blockIdx.x;
    int t = threadIdx.x;
    int base  = bbase[b];
    int count = bhist[b];
    int node0 = b << BSH;

    for (int r = t; r < BS; r += 256) lcnt[r] = 0;
    __syncthreads();
    for (int i = t; i < count; i += 256)
        atomicAdd(&lcnt[staging[base + i] & (BS - 1)], 1);
    __syncthreads();

    // exclusive scan of lcnt[512] with 256 threads
    int a0 = lcnt[2 * t], a1 = lcnt[2 * t + 1];
    int pair = a0 + a1;
    ps[t] = pair;
    __syncthreads();
    for (int d = 1; d < 256; d <<= 1) {
        int x = (t >= d) ? ps[t - d] : 0;
        __syncthreads();
        ps[t] += x;
        __syncthreads();
    }
    int excl = ps[t] - pair;
    loff[2 * t]     = excl;
    loff[2 * t + 1] = excl + a0;
    __syncthreads();

    for (int r = t; r < BS; r += 256) {
        int node = node0 + r;
        if (node < Nn) {
            int c = lcnt[r];
            cnt[node] = c;
            off[node] = base + loff[r];
            nrm[node] = rsqrtf((float)c + 1.0f);
        }
        lcur[r] = 0;
    }
    __syncthreads();

    for (int i = t; i < count; i += 256) {
        int v = staging[base + i];
        int r = v & (BS - 1);
        int p = base + loff[r] + atomicAdd(&lcur[r], 1);
        csr[p] = v >> BSH;
    }
}

// ---------------- register-tiled f32 GEMM, v5 ----------------
// History:
//  v1 (round 0): 67us/gemm, FETCH 32MB, VALUBusy 21%, Occ 23%. Latency-bound.
//  v2/v3 (rounds 1-2): geometry changes hit a node-level pathology (3.36GB
//     device traffic, duration independent of occupancy). Reverted; round 3
//     confirmed healthy node with v1 geometry.
//  v4 (round 3): kk-unroll 8 -> gemms out of top-5. PROVEN BODY - DO NOT
//     RESTRUCTURE. v5 only adds an optional bf16-packing epilogue (BF16OUT)
//     so gather inputs (h1, p) can be half-width.
template<int K, int N, bool PRESCALE, bool BIAS, bool BF16OUT>
__global__ void gemm_tiled(const float* __restrict__ A, const float* __restrict__ B,
                           const float* __restrict__ nrm, const float* __restrict__ bias,
                           void* __restrict__ Cv, int M) {
    constexpr int CT = N / 8;
    constexpr int RB = (256 / CT) * 4;
    __shared__ float Ws[K * N];

    int tid = threadIdx.x;
    for (int i = tid; i < K * N / 4; i += 256)
        ((float4*)Ws)[i] = ((const float4*)B)[i];
    __syncthreads();

    int ct = tid % CT;
    int rt = tid / CT;
    int row0 = blockIdx.x * RB + rt * 4;
    int c0 = ct * 8;

    float acc[4][8];
#pragma unroll
    for (int r = 0; r < 4; r++)
#pragma unroll
        for (int c = 0; c < 8; c++) acc[r][c] = 0.f;

    for (int kk = 0; kk < K; kk += 8) {
        float4 av[4], av2[4];
#pragma unroll
        for (int r = 0; r < 4; r++) {
            int row = row0 + r;
            if (row < M) {
                av[r]  = *(const float4*)(A + (size_t)row * K + kk);
                av2[r] = *(const float4*)(A + (size_t)row * K + kk + 4);
            } else {
                av[r]  = make_float4(0.f, 0.f, 0.f, 0.f);
                av2[r] = make_float4(0.f, 0.f, 0.f, 0.f);
            }
        }
#pragma unroll
        for (int j = 0; j < 4; j++) {
            const float* wrow = Ws + (kk + j) * N + c0;
            float4 w0 = *(const float4*)(wrow);
            float4 w1 = *(const float4*)(wrow + 4);
            float wj[8] = {w0.x, w0.y, w0.z, w0.w, w1.x, w1.y, w1.z, w1.w};
#pragma unroll
            for (int r = 0; r < 4; r++) {
                float a = (j == 0) ? av[r].x : (j == 1) ? av[r].y : (j == 2) ? av[r].z : av[r].w;
#pragma unroll
                for (int c = 0; c < 8; c++)
                    acc[r][c] = fmaf(a, wj[c], acc[r][c]);
            }
        }
#pragma unroll
        for (int j = 0; j < 4; j++) {
            const float* wrow = Ws + (kk + 4 + j) * N + c0;
            float4 w0 = *(const float4*)(wrow);
            float4 w1 = *(const float4*)(wrow + 4);
            float wj[8] = {w0.x, w0.y, w0.z, w0.w, w1.x, w1.y, w1.z, w1.w};
#pragma unroll
            for (int r = 0; r < 4; r++) {
                float a = (j == 0) ? av2[r].x : (j == 1) ? av2[r].y : (j == 2) ? av2[r].z : av2[r].w;
#pragma unroll
                for (int c = 0; c < 8; c++)
                    acc[r][c] = fmaf(a, wj[c], acc[r][c]);
            }
        }
    }

    float bcol[8];
    if (BIAS) {
        float4 bb0 = *(const float4*)(bias + c0);
        float4 bb1 = *(const float4*)(bias + c0 + 4);
        bcol[0]=bb0.x; bcol[1]=bb0.y; bcol[2]=bb0.z; bcol[3]=bb0.w;
        bcol[4]=bb1.x; bcol[5]=bb1.y; bcol[6]=bb1.z; bcol[7]=bb1.w;
    }

#pragma unroll
    for (int r = 0; r < 4; r++) {
        int row = row0 + r;
        if (row >= M) continue;
        float scale = PRESCALE ? nrm[row] : 1.0f;
        float o[8];
#pragma unroll
        for (int c = 0; c < 8; c++) {
            float v = acc[r][c];
            if (PRESCALE) v *= scale;
            if (BIAS)     v += bcol[c];
            o[c] = v;
        }
        if (BF16OUT) {
            unsigned int pk0 = (unsigned int)f2bf(o[0]) | ((unsigned int)f2bf(o[1]) << 16);
            unsigned int pk1 = (unsigned int)f2bf(o[2]) | ((unsigned int)f2bf(o[3]) << 16);
            unsigned int pk2 = (unsigned int)f2bf(o[4]) | ((unsigned int)f2bf(o[5]) << 16);
            unsigned int pk3 = (unsigned int)f2bf(o[6]) | ((unsigned int)f2bf(o[7]) << 16);
            uint4 pk; pk.x = pk0; pk.y = pk1; pk.z = pk2; pk.w = pk3;
            *(uint4*)((unsigned short*)Cv + (size_t)row * N + c0) = pk;
        } else {
            float4 o0, o1;
            o0.x = o[0]; o0.y = o[1]; o0.z = o[2]; o0.w = o[3];
            o1.x = o[4]; o1.y = o[5]; o1.z = o[6]; o1.w = o[7];
            float* crow = (float*)Cv + (size_t)row * N + c0;
            *(float4*)(crow) = o0;
            *(float4*)(crow + 4) = o1;
        }
    }
}

// ---------------- per-node CSR gather (bf16 h): ONE WAVE PER NODE ----------------
// h rows are 64 x bf16 = 128B; lane loads 2B (coalesced 128B/wave request).
// Round-3 counters: f32 gather = 60.3us, FETCH 195MB, VALUBusy 13%, Occ 71%
// -> bound by bytes/edge. bf16 halves bytes; unroll deepened to 16 so the
// request rate can double to keep the same B/s.
// CONV (-> bf16 p):  out_i = norm_i * relu( norm_i*(sum + self) + bias )
// !CONV (-> f32 q):  out_i = norm_i * (sum + self)
template<bool CONV>
__global__ void gather64_kernel(const unsigned short* __restrict__ h,
                                const float* __restrict__ norm,
                                const int* __restrict__ off, const int* __restrict__ cnt,
                                const int* __restrict__ csr_src,
                                const float* __restrict__ bias,
                                void* __restrict__ outv, int Nn, int E) {
    int wave = (blockIdx.x * blockDim.x + threadIdx.x) >> 6;
    int lane = threadIdx.x & 63;
    int node = __builtin_amdgcn_readfirstlane(wave);
    if (node >= Nn) return;

    int o0 = __builtin_amdgcn_readfirstlane(off[node]);
    int c  = __builtin_amdgcn_readfirstlane(cnt[node]);
    if (c < 0) c = 0;
    if (o0 < 0) o0 = 0;
    if (o0 + c > E) c = E - o0;

    const int* ce = csr_src + o0;
    float sum = 0.0f;
    int e = 0;
    for (; e + 16 <= c; e += 16) {
        int si[16];
        unsigned short v[16];
#pragma unroll
        for (int u = 0; u < 16; u++) si[u] = clampi(ce[e + u], 0, Nn - 1);
#pragma unroll
        for (int u = 0; u < 16; u++) v[u] = h[(size_t)si[u] * 64 + lane];
#pragma unroll
        for (int u = 0; u < 16; u++) sum += bf2f(v[u]);
    }
    for (; e + 8 <= c; e += 8) {
        int si[8];
        unsigned short v[8];
#pragma unroll
        for (int u = 0; u < 8; u++) si[u] = clampi(ce[e + u], 0, Nn - 1);
#pragma unroll
        for (int u = 0; u < 8; u++) v[u] = h[(size_t)si[u] * 64 + lane];
#pragma unroll
        for (int u = 0; u < 8; u++) sum += bf2f(v[u]);
    }
    for (; e + 4 <= c; e += 4) {
        int si[4];
        unsigned short v[4];
#pragma unroll
        for (int u = 0; u < 4; u++) si[u] = clampi(ce[e + u], 0, Nn - 1);
#pragma unroll
        for (int u = 0; u < 4; u++) v[u] = h[(size_t)si[u] * 64 + lane];
#pragma unroll
        for (int u = 0; u < 4; u++) sum += bf2f(v[u]);
    }
    for (; e < c; e++) {
        int s = clampi(ce[e], 0, Nn - 1);
        sum += bf2f(h[(size_t)s * 64 + lane]);
    }
    float self = bf2f(h[(size_t)node * 64 + lane]);
    float nv = norm[node];
    float r = nv * (sum + self);
    if (CONV) {
        r = nv * fmaxf(r + bias[lane], 0.0f);
        ((unsigned short*)outv)[(size_t)node * 64 + lane] = f2bf(r);
    } else {
        ((float*)outv)[(size_t)node * 64 + lane] = r;
    }
}

extern "C" void kernel_launch(void* const* d_in, const int* in_sizes, int n_in,
                              void* d_out, int out_size, void* d_ws, size_t ws_size,
                              hipStream_t stream) {
    if (n_in < 6) return;
    const float* x   = (const float*)d_in[0];   // [N,128] f32
    const int*   ei  = (const int*)d_in[1];     // [2,E] int32
    const float* W1  = (const float*)d_in[2];   // [128,64] f32
    const float* b1  = (const float*)d_in[3];   // [64] f32
    const float* W2  = (const float*)d_in[4];   // [64,128] f32
    const float* b2  = (const float*)d_in[5];   // [128] f32
    float*       out = (float*)d_out;           // [N,128] f32

    int Nn = in_sizes[0] / F_IN;
    int E  = in_sizes[1] / 2;
    const int* src = ei;
    const int* dst = ei + E;

    int NB = (Nn + BS - 1) >> BSH;              // 196 for 100k
    if (NB > MAXNB) return;
    if (Nn > (1 << (31 - BSH))) return;

    // ---- workspace layout (~40 MB), guarded ----
    size_t o = 0;
    auto alloc = [&](size_t bytes) { size_t cur = o; o += (bytes + 255) & ~(size_t)255; return cur; };
    size_t o_cnt   = alloc((size_t)Nn * 4);
    size_t o_off   = alloc((size_t)Nn * 4);
    size_t o_nrm   = alloc((size_t)Nn * 4);
    size_t o_csr   = alloc((size_t)E * 4);
    size_t o_stg   = alloc((size_t)E * 4);
    size_t o_bh    = alloc(MAXNB * 4);
    size_t o_bb    = alloc(MAXNB * 4);
    size_t o_bc    = alloc(MAXNB * 4);
    size_t o_h     = alloc((size_t)Nn * F_HID * 4);   // q (f32) overlays h1 (bf16)
    if (o > ws_size) return;

    char* ws = (char*)d_ws;
    int*   cnt   = (int*)(ws + o_cnt);
    int*   off   = (int*)(ws + o_off);
    float* nrm   = (float*)(ws + o_nrm);
    int*   csr   = (int*)(ws + o_csr);
    int*   stg   = (int*)(ws + o_stg);
    int*   bh    = (int*)(ws + o_bh);
    int*   bb    = (int*)(ws + o_bb);
    int*   bc    = (int*)(ws + o_bc);
    unsigned short* h1 = (unsigned short*)(ws + o_h);         // [Nn,64] bf16
    float*          q  = (float*)(ws + o_h);                  // [Nn,64] f32, h1 dead by then
    unsigned short* p  = (unsigned short*)(out + (size_t)Nn * F_HID); // bf16, upper half of d_out

    // ---- CSR build (bucketed, write-local) ----
    zero2_kernel<<<1, 256, 0, stream>>>(bh, bc, MAXNB);
    bhist_kernel<<<256, 256, 0, stream>>>(dst, bh, E, Nn, NB);
    bscan_kernel<<<1, 256, 0, stream>>>(bh, bb, NB);
    bplace_kernel<<<256, 256, 0, stream>>>(src, dst, bb, bc, stg, E, Nn, NB);
    bfine_kernel<<<NB, 256, 0, stream>>>(bh, bb, stg, cnt, off, nrm, csr, Nn);

    // ---- layer 1: h1 = bf16((x@W1)*norm) ; p = bf16(norm*relu(norm*(sum+self)+b1)) ----
    {
        constexpr int RB = (256 / (F_HID / 8)) * 4;  // 128 rows/block -> 782 blocks
        gemm_tiled<F_IN, F_HID, true, false, true><<<(Nn + RB - 1) / RB, 256, 0, stream>>>(
            x, W1, nrm, nullptr, h1, Nn);
    }
    gather64_kernel<true><<<(Nn + 3) / 4, 256, 0, stream>>>(
        h1, nrm, off, cnt, csr, b1, p, Nn, E);

    // ---- layer 2: q = norm*(sum_p+p) ; out = q@W2 + b2 ----
    gather64_kernel<false><<<(Nn + 3) / 4, 256, 0, stream>>>(
        p, nrm, off, cnt, csr, nullptr, q, Nn, E);
    {
        constexpr int RB = (256 / (F_OUT / 8)) * 4;  // 64 rows/block -> 1563 blocks
        gemm_tiled<F_HID, F_OUT, false, true, false><<<(Nn + RB - 1) / RB, 256, 0, stream>>>(
            q, W2, nullptr, b2, out, Nn);
    }
}